// Round 7
// baseline (159.894 us; speedup 1.0000x reference)
//
#include <hip/hip_runtime.h>
#include <hip/hip_bf16.h>
#include <math.h>
#include <stdint.h>

typedef __hip_bfloat16 bf16;
typedef __attribute__((ext_vector_type(8))) short short8;
typedef __attribute__((ext_vector_type(4))) float f32x4;
typedef __attribute__((ext_vector_type(16))) float f32x16;

#define NB 2
#define NS 2048
#define ND 1024
#define NH 16
#define NHD 64
#define N3D 3072

// softmax scale folded into exp2 domain: (1/sqrt(64)) * log2(e)
#define SM_SCALE 0.18033688011112042f

// ---------------- async global->LDS, 16B per lane ----------------
__device__ __forceinline__ void gload16(const bf16* g, void* l) {
  __builtin_amdgcn_global_load_lds(
      (const __attribute__((address_space(1))) uint32_t*)g,
      (__attribute__((address_space(3))) uint32_t*)l, 16, 0, 0);
}

// ---------------- fp32 -> bf16 cast (4-wide) ----------------
__global__ void cast_kernel(const float4* __restrict__ in, bf16* __restrict__ out, int n4) {
  int i = blockIdx.x * blockDim.x + threadIdx.x;
  if (i >= n4) return;
  float4 v = in[i];
  alignas(8) bf16 r[4];
  r[0] = __float2bfloat16(v.x);
  r[1] = __float2bfloat16(v.y);
  r[2] = __float2bfloat16(v.z);
  r[3] = __float2bfloat16(v.w);
  *reinterpret_cast<uint2*>(out + (size_t)i * 4) = *reinterpret_cast<const uint2*>(r);
}

// ---------------- RoPE cos/sin tables: [S][32] each ----------------
__global__ void ropetab_kernel(float* __restrict__ cs_tab, float* __restrict__ sn_tab) {
  int idx = blockIdx.x * blockDim.x + threadIdx.x;  // 65536
  int j = idx & 31;
  int s = idx >> 5;
  float inv = exp2f((float)(2 * j) * (-13.287712379549449f / 64.0f));
  float ang = (float)s * inv;
  float sn, cs;
  sincosf(ang, &sn, &cs);
  cs_tab[idx] = cs;
  sn_tab[idx] = sn;
}

// ---------------- QKV GEMM with fused RoPE epilogue ----------------
__global__ __launch_bounds__(256) void gemm_qkv(const bf16* __restrict__ A,
                                                const bf16* __restrict__ Bm,
                                                const float* __restrict__ cs_tab,
                                                const float* __restrict__ sn_tab,
                                                bf16* __restrict__ Qr, bf16* __restrict__ Kr,
                                                bf16* __restrict__ Vtmp) {
  __shared__ short As[128 * 64];
  __shared__ short Bs[128 * 64];
  const int K = ND;
  const int tid = threadIdx.x;
  const int lane = tid & 63;
  const int w = tid >> 6;
  const int wr = w >> 1, wc = w & 1;
  const int l15 = lane & 15, l4 = lane >> 4;
  const int bn0 = blockIdx.x * 128, bm0 = blockIdx.y * 128;
  const int srow = w * 8 + (lane >> 3);
  const int scol = (lane & 7) * 8;
  f32x4 acc[4][4] = {};
  for (int k0 = 0; k0 < K; k0 += 64) {
    __syncthreads();
#pragma unroll
    for (int i = 0; i < 4; ++i) {
      gload16(&A[(size_t)(bm0 + i * 32 + srow) * K + k0 + scol], &As[(i * 32 + w * 8) * 64]);
      gload16(&Bm[(size_t)(bn0 + i * 32 + srow) * K + k0 + scol], &Bs[(i * 32 + w * 8) * 64]);
    }
    __syncthreads();
#pragma unroll
    for (int kk = 0; kk < 64; kk += 32) {
      short8 am[4], bn[4];
#pragma unroll
      for (int t = 0; t < 4; ++t) {
        am[t] = *reinterpret_cast<const short8*>(&As[(wr * 64 + t * 16 + l15) * 64 + kk + l4 * 8]);
        bn[t] = *reinterpret_cast<const short8*>(&Bs[(wc * 64 + t * 16 + l15) * 64 + kk + l4 * 8]);
      }
#pragma unroll
      for (int m = 0; m < 4; ++m)
#pragma unroll
        for (int n = 0; n < 4; ++n)
          acc[m][n] = __builtin_amdgcn_mfma_f32_16x16x32_bf16(am[m], bn[n], acc[m][n], 0, 0, 0);
    }
  }
  const int colbase = bn0 + wc * 64;  // 64-aligned
  const int region = colbase >> 10;   // 0=Q, 1=K, 2=V
  if (region < 2) {
    bf16* dst = region ? Kr : Qr;
    const int h = (colbase & 1023) >> 6;
#pragma unroll
    for (int m = 0; m < 4; ++m)
#pragma unroll
      for (int n = 0; n < 2; ++n)
#pragma unroll
        for (int r = 0; r < 4; ++r) {
          int row = bm0 + wr * 64 + m * 16 + l4 * 4 + r;
          int b = row >> 11, s = row & (NS - 1);
          int j = n * 16 + l15;  // [0,32)
          float cs = cs_tab[s * 32 + j], sn = sn_tab[s * 32 + j];
          float v0 = acc[m][n][r], v1 = acc[m][n + 2][r];
          size_t base = ((size_t)(b * NH + h) * NS + s) * NHD + j;
          dst[base] = __float2bfloat16(v0 * cs - v1 * sn);
          dst[base + 32] = __float2bfloat16(v1 * cs + v0 * sn);
        }
  } else {
#pragma unroll
    for (int m = 0; m < 4; ++m)
#pragma unroll
      for (int n = 0; n < 4; ++n)
#pragma unroll
        for (int r = 0; r < 4; ++r) {
          int row = bm0 + wr * 64 + m * 16 + l4 * 4 + r;
          int col = colbase + n * 16 + l15 - 2048;
          Vtmp[(size_t)row * ND + col] = __float2bfloat16(acc[m][n][r]);
        }
  }
}

// ---------------- generic bf16 GEMM (out-proj): C[M,N] = A[M,K] * B[N,K]^T ----------------
__global__ __launch_bounds__(256) void gemm_bt(const bf16* __restrict__ A,
                                               const bf16* __restrict__ Bm,
                                               float* __restrict__ Cv,
                                               int M, int N, int K) {
  __shared__ short As[128 * 64];
  __shared__ short Bs[128 * 64];
  const int tid = threadIdx.x;
  const int lane = tid & 63;
  const int w = tid >> 6;
  const int wr = w >> 1, wc = w & 1;
  const int l15 = lane & 15, l4 = lane >> 4;
  const int bn0 = blockIdx.x * 128, bm0 = blockIdx.y * 128;
  const int srow = w * 8 + (lane >> 3);
  const int scol = (lane & 7) * 8;
  f32x4 acc[4][4] = {};
  for (int k0 = 0; k0 < K; k0 += 64) {
    __syncthreads();
#pragma unroll
    for (int i = 0; i < 4; ++i) {
      gload16(&A[(size_t)(bm0 + i * 32 + srow) * K + k0 + scol], &As[(i * 32 + w * 8) * 64]);
      gload16(&Bm[(size_t)(bn0 + i * 32 + srow) * K + k0 + scol], &Bs[(i * 32 + w * 8) * 64]);
    }
    __syncthreads();
#pragma unroll
    for (int kk = 0; kk < 64; kk += 32) {
      short8 am[4], bn[4];
#pragma unroll
      for (int t = 0; t < 4; ++t) {
        am[t] = *reinterpret_cast<const short8*>(&As[(wr * 64 + t * 16 + l15) * 64 + kk + l4 * 8]);
        bn[t] = *reinterpret_cast<const short8*>(&Bs[(wc * 64 + t * 16 + l15) * 64 + kk + l4 * 8]);
      }
#pragma unroll
      for (int m = 0; m < 4; ++m)
#pragma unroll
        for (int n = 0; n < 4; ++n)
          acc[m][n] = __builtin_amdgcn_mfma_f32_16x16x32_bf16(am[m], bn[n], acc[m][n], 0, 0, 0);
    }
  }
#pragma unroll
  for (int m = 0; m < 4; ++m)
#pragma unroll
    for (int n = 0; n < 4; ++n)
#pragma unroll
      for (int r = 0; r < 4; ++r) {
        int row = bm0 + wr * 64 + m * 16 + l4 * 4 + r;
        int col = bn0 + wc * 64 + n * 16 + l15;
        Cv[(size_t)row * N + col] = acc[m][n][r];
      }
}

// ---------------- V transpose: Vtmp [4096,1024] -> Vt (bf16 [B,H,HD,S]) ----------------
__global__ __launch_bounds__(256) void vtrans_kernel(const bf16* __restrict__ Vtmp,
                                                     bf16* __restrict__ Vt) {
  int bh = blockIdx.y;
  int b = bh >> 4, h = bh & 15;
  int s0 = blockIdx.x * 64;
  __shared__ bf16 tile[64][72];
#pragma unroll
  for (int it = 0; it < 16; ++it) {
    int e = it * 256 + threadIdx.x;
    int sr = e >> 6, hd = e & 63;
    tile[sr][hd] = Vtmp[(size_t)(b * NS + s0 + sr) * ND + h * NHD + hd];
  }
  __syncthreads();
#pragma unroll
  for (int it = 0; it < 16; ++it) {
    int e = it * 256 + threadIdx.x;
    int hd = e >> 6, sc = e & 63;
    Vt[((size_t)bh * NHD + hd) * NS + s0 + sc] = tile[sc][hd];
  }
}

// ---------------- attn_mask -> float bias ----------------
__global__ void maskbias_kernel(const int* __restrict__ amask, float* __restrict__ mb, int n) {
  int i = blockIdx.x * blockDim.x + threadIdx.x;
  if (i < n) mb[i] = amask[i] ? 0.f : -1e30f;
}

// ---------------- causal flash attention: 2-wave blocks, 4 blocks/CU ----------------
// One block = 64 q-rows (2 waves x 32), KVBLK=64 double-buffered LDS (T2 XOR swizzle).
// 1024 blocks -> 4 independent barrier domains/CU so stalls overlap. LPT dispatch,
// 4 heads pinned per XCD slot (~2MB L2 set). 32x32 swapped-QK^T; in-register softmax
// (T12 cvt_pk+permlane32_swap); T13 defer-max; T5 setprio around MFMA clusters.
__global__ __launch_bounds__(128, 2) void attn_kernel(const bf16* __restrict__ Qr,
                                                      const bf16* __restrict__ Kr,
                                                      const bf16* __restrict__ Vt,
                                                      const float* __restrict__ mb,
                                                      bf16* __restrict__ AO) {
  __shared__ short Ks[2][64 * 64];
  __shared__ short Vs[2][64 * 64];
  __shared__ float Mb[2][64];

  const int tid = threadIdx.x;
  const int lane = tid & 63;
  const int w = tid >> 6;  // 0..1
  const int q = lane & 31;
  const int hi = lane >> 5;

  const int lin = blockIdx.x;        // 0..1023
  const int xcd = lin & 7;
  const int k = lin >> 3;            // 0..127
  const int bh = xcd * 4 + (k & 3);  // 4 heads per XCD slot
  const int tile = 31 - (k >> 2);    // longest first (LPT)
  const int b = bh >> 4, h = bh & 15;
  const int qw = tile * 64 + w * 32;
  const int nc = tile + 1;

  const bf16* Qb = Qr + (size_t)bh * NS * NHD;
  const bf16* Kb = Kr + (size_t)bh * NS * NHD;
  const bf16* Vb = Vt + (size_t)bh * NHD * NS;

  // staging: 128 threads x 4 x 16B cover 64x64 shorts
  const int srow = tid >> 1;        // 0..63
  const int sc0 = (tid & 1) * 32;   // shorts
  const int swz = (srow & 7) << 3;  // XOR swizzle (shorts)

  short8 Qf[4];
#pragma unroll
  for (int s = 0; s < 4; ++s)
    Qf[s] = *reinterpret_cast<const short8*>(&Qb[(size_t)(qw + q) * NHD + s * 16 + hi * 8]);

  f32x16 o0 = {}, o1 = {};
  float mx = -1e30f, lsum = 0.f;

  short8 kreg[4], vreg[4];
  float4 mreg;
  auto prefetch = [&](int kv0) {
#pragma unroll
    for (int g = 0; g < 4; ++g) {
      kreg[g] = *reinterpret_cast<const short8*>(&Kb[(size_t)(kv0 + srow) * NHD + sc0 + g * 8]);
      vreg[g] = *reinterpret_cast<const short8*>(&Vb[(size_t)srow * NS + kv0 + sc0 + g * 8]);
    }
    if (tid < 16) mreg = *reinterpret_cast<const float4*>(&mb[b * NS + kv0 + tid * 4]);
  };
  auto stage = [&](int buf) {
#pragma unroll
    for (int g = 0; g < 4; ++g) {
      *reinterpret_cast<short8*>(&Ks[buf][srow * 64 + ((sc0 + g * 8) ^ swz)]) = kreg[g];
      *reinterpret_cast<short8*>(&Vs[buf][srow * 64 + ((sc0 + g * 8) ^ swz)]) = vreg[g];
    }
    if (tid < 16) *reinterpret_cast<float4*>(&Mb[buf][tid * 4]) = mreg;
  };

  prefetch(0);
  stage(0);
  __syncthreads();

  const int rsw = (q & 7) << 3;

  for (int c = 0; c < nc; ++c) {
    const int cur = c & 1;
    const int kv0 = c * 64;
    if (c + 1 < nc) prefetch((c + 1) * 64);

    if (kv0 < qw + 32) {
      f32x16 a0 = {}, a1 = {};
      __builtin_amdgcn_s_setprio(1);
#pragma unroll
      for (int s = 0; s < 4; ++s) {
        short8 kf0 = *reinterpret_cast<const short8*>(
            &Ks[cur][q * 64 + ((s * 16 + hi * 8) ^ rsw)]);
        short8 kf1 = *reinterpret_cast<const short8*>(
            &Ks[cur][(32 + q) * 64 + ((s * 16 + hi * 8) ^ rsw)]);
        a0 = __builtin_amdgcn_mfma_f32_32x32x16_bf16(kf0, Qf[s], a0, 0, 0, 0);
        a1 = __builtin_amdgcn_mfma_f32_32x32x16_bf16(kf1, Qf[s], a1, 0, 0, 0);
      }
      __builtin_amdgcn_s_setprio(0);

      float4 bv[2][4];
#pragma unroll
      for (int t = 0; t < 2; ++t)
#pragma unroll
        for (int g = 0; g < 4; ++g)
          bv[t][g] = *reinterpret_cast<const float4*>(&Mb[cur][t * 32 + g * 8 + hi * 4]);
      const int qg = qw + q;
#pragma unroll
      for (int t = 0; t < 2; ++t) {
        f32x16& a = t ? a1 : a0;
        const bool needc = (kv0 + t * 32 + 31 > qw);
#pragma unroll
        for (int r = 0; r < 16; ++r) {
          float v = fmaf(a[r], SM_SCALE, ((const float*)&bv[t][r >> 2])[r & 3]);
          if (needc) {
            int kvg = kv0 + t * 32 + (r & 3) + 8 * (r >> 2) + 4 * hi;
            if (kvg > qg) v = -1e30f;
          }
          a[r] = v;
        }
      }

      float cm = a0[0];
#pragma unroll
      for (int r = 1; r < 16; ++r) cm = fmaxf(cm, a0[r]);
#pragma unroll
      for (int r = 0; r < 16; ++r) cm = fmaxf(cm, a1[r]);
      float pm = fmaxf(cm, __shfl_xor(cm, 32));

      if (!__all(pm <= mx + 8.f)) {
        float mn = fmaxf(mx, pm);
        float fac = __builtin_amdgcn_exp2f(mx - mn);
        mx = mn;
        lsum *= fac;
#pragma unroll
        for (int r = 0; r < 16; ++r) {
          float fq = __shfl(fac, (r & 3) + 8 * (r >> 2) + 4 * hi);
          o0[r] *= fq;
          o1[r] *= fq;
        }
      }

      float rs = 0.f;
      short8 pa[4];
#pragma unroll
      for (int t = 0; t < 2; ++t) {
        f32x16& a = t ? a1 : a0;
#pragma unroll
        for (int r = 0; r < 16; ++r) {
          float e = __builtin_amdgcn_exp2f(a[r] - mx);
          a[r] = e;
          rs += e;
        }
#pragma unroll
        for (int g = 0; g < 2; ++g) {
          union { unsigned int u; __hip_bfloat162 h2; } X, X2, Y, Y2;
          X.h2 = __float22bfloat162_rn(float2{a[g * 8 + 0], a[g * 8 + 1]});
          X2.h2 = __float22bfloat162_rn(float2{a[g * 8 + 2], a[g * 8 + 3]});
          Y.h2 = __float22bfloat162_rn(float2{a[g * 8 + 4], a[g * 8 + 5]});
          Y2.h2 = __float22bfloat162_rn(float2{a[g * 8 + 6], a[g * 8 + 7]});
          asm volatile("v_permlane32_swap_b32 %0, %1" : "+v"(X.u), "+v"(Y.u));
          asm volatile("v_permlane32_swap_b32 %0, %1" : "+v"(X2.u), "+v"(Y2.u));
          union { unsigned int u[4]; short8 s; } P;
          P.u[0] = X.u;
          P.u[1] = X2.u;
          P.u[2] = Y.u;
          P.u[3] = Y2.u;
          pa[t * 2 + g] = P.s;
        }
      }
      lsum += rs + __shfl_xor(rs, 32);

      __builtin_amdgcn_s_setprio(1);
#pragma unroll
      for (int ks = 0; ks < 4; ++ks) {
        const int vcol = (ks * 16 + hi * 8) ^ rsw;
        short8 vf0 = *reinterpret_cast<const short8*>(&Vs[cur][q * 64 + vcol]);
        short8 vf1 = *reinterpret_cast<const short8*>(&Vs[cur][(32 + q) * 64 + vcol]);
        o0 = __builtin_amdgcn_mfma_f32_32x32x16_bf16(pa[ks], vf0, o0, 0, 0, 0);
        o1 = __builtin_amdgcn_mfma_f32_32x32x16_bf16(pa[ks], vf1, o1, 0, 0, 0);
      }
      __builtin_amdgcn_s_setprio(0);
    }

    if (c + 1 < nc) stage(cur ^ 1);
    __syncthreads();
  }

  float inv = 1.0f / lsum;
#pragma unroll
  for (int r = 0; r < 16; ++r) {
    const int crow = (r & 3) + 8 * (r >> 2) + 4 * hi;
    float iq = __shfl(inv, crow);
    size_t base = (size_t)(b * NS + qw + crow) * ND + h * NHD;
    AO[base + q] = __float2bfloat16(o0[r] * iq);
    AO[base + 32 + q] = __float2bfloat16(o1[r] * iq);
  }
}

extern "C" void kernel_launch(void* const* d_in, const int* in_sizes, int n_in,
                              void* d_out, int out_size, void* d_ws, size_t ws_size,
                              hipStream_t stream) {
  const float* x = (const float*)d_in[0];
  const int* amask = (const int*)d_in[1];
  const float* Wqkv = (const float*)d_in[2];
  const float* Wout = (const float*)d_in[3];
  float* out = (float*)d_out;

  char* p = (char*)d_ws;
  bf16* xb = (bf16*)(p);                  // 8,388,608
  bf16* wqkvb = (bf16*)(p + 8388608);     // 6,291,456 (dead after gemm_qkv)
  bf16* woutb = (bf16*)(p + 14680064);    // 2,097,152
  bf16* Vtmp = (bf16*)(p + 16777216);     // 8,388,608 -> 25,165,824
  float* cs_tab = (float*)(p + 25165824); // 262,144
  float* sn_tab = (float*)(p + 25427968); // 262,144 -> 25,690,112
  bf16* Qr = (bf16*)(p + 41943040);       // 8,388,608
  bf16* Kr = (bf16*)(p + 50331648);       // 8,388,608
  bf16* Vt = (bf16*)(p + 58720256);       // 8,388,608 -> 67,108,864 end
  bf16* AO = xb;                          // aliases xb (dead after gemm_qkv)
  float* mbias = (float*)(p + 8388608);   // aliases wqkvb (dead after gemm_qkv)

  cast_kernel<<<4096, 256, 0, stream>>>((const float4*)x, xb, (NB * NS * ND) / 4);
  cast_kernel<<<3072, 256, 0, stream>>>((const float4*)Wqkv, wqkvb, (N3D * ND) / 4);
  cast_kernel<<<1024, 256, 0, stream>>>((const float4*)Wout, woutb, (ND * ND) / 4);
  ropetab_kernel<<<256, 256, 0, stream>>>(cs_tab, sn_tab);

  gemm_qkv<<<dim3(N3D / 128, (NB * NS) / 128), 256, 0, stream>>>(xb, wqkvb, cs_tab, sn_tab,
                                                                 Qr, Kr, Vtmp);
  vtrans_kernel<<<dim3(NS / 64, NB * NH), 256, 0, stream>>>(Vtmp, Vt);
  maskbias_kernel<<<16, 256, 0, stream>>>(amask, mbias, NB * NS);
  attn_kernel<<<1024, 128, 0, stream>>>(Qr, Kr, Vt, mbias, AO);
  gemm_bt<<<dim3(ND / 128, (NB * NS) / 128), 256, 0, stream>>>(AO, woutb, out,
                                                               NB * NS, ND, ND);
}

// Round 8
// 156.750 us; speedup vs baseline: 1.0201x; 1.0201x over previous
//
#include <hip/hip_runtime.h>
#include <hip/hip_bf16.h>
#include <math.h>
#include <stdint.h>

typedef __hip_bfloat16 bf16;
typedef __attribute__((ext_vector_type(8))) short short8;
typedef __attribute__((ext_vector_type(4))) float f32x4;
typedef __attribute__((ext_vector_type(16))) float f32x16;

#define NB 2
#define NS 2048
#define ND 1024
#define NH 16
#define NHD 64
#define N3D 3072

// softmax scale folded into exp2 domain: (1/sqrt(64)) * log2(e)
#define SM_SCALE 0.18033688011112042f

// ---------------- async global->LDS, 16B per lane ----------------
__device__ __forceinline__ void gload16(const bf16* g, void* l) {
  __builtin_amdgcn_global_load_lds(
      (const __attribute__((address_space(1))) uint32_t*)g,
      (__attribute__((address_space(3))) uint32_t*)l, 16, 0, 0);
}

// ---------------- fp32 -> bf16 cast (4-wide) ----------------
__global__ void cast_kernel(const float4* __restrict__ in, bf16* __restrict__ out, int n4) {
  int i = blockIdx.x * blockDim.x + threadIdx.x;
  if (i >= n4) return;
  float4 v = in[i];
  alignas(8) bf16 r[4];
  r[0] = __float2bfloat16(v.x);
  r[1] = __float2bfloat16(v.y);
  r[2] = __float2bfloat16(v.z);
  r[3] = __float2bfloat16(v.w);
  *reinterpret_cast<uint2*>(out + (size_t)i * 4) = *reinterpret_cast<const uint2*>(r);
}

// ---------------- RoPE cos/sin tables: [S][32] each ----------------
__global__ void ropetab_kernel(float* __restrict__ cs_tab, float* __restrict__ sn_tab) {
  int idx = blockIdx.x * blockDim.x + threadIdx.x;  // 65536
  int j = idx & 31;
  int s = idx >> 5;
  float inv = exp2f((float)(2 * j) * (-13.287712379549449f / 64.0f));
  float ang = (float)s * inv;
  float sn, cs;
  sincosf(ang, &sn, &cs);
  cs_tab[idx] = cs;
  sn_tab[idx] = sn;
}

// ---------------- QKV GEMM with fused RoPE epilogue ----------------
// XCD-rect swizzle: grid 24x32 tiles; each XCD owns a 12x8 rect ->
// per-XCD L2 set = 8 A-panels (2MB) + 12 B-panels (3MB) ~ L2-resident.
__global__ __launch_bounds__(256) void gemm_qkv(const bf16* __restrict__ A,
                                                const bf16* __restrict__ Bm,
                                                const float* __restrict__ cs_tab,
                                                const float* __restrict__ sn_tab,
                                                bf16* __restrict__ Qr, bf16* __restrict__ Kr,
                                                bf16* __restrict__ Vtmp) {
  __shared__ short As[128 * 64];
  __shared__ short Bs[128 * 64];
  const int K = ND;
  const int tid = threadIdx.x;
  const int lane = tid & 63;
  const int w = tid >> 6;
  const int wr = w >> 1, wc = w & 1;
  const int l15 = lane & 15, l4 = lane >> 4;
  // bijective XCD-rect remap (GX=24, GY=32): xcd gets 12x x 8y tiles
  const int lin = blockIdx.y * 24 + blockIdx.x;
  const int xcd = lin & 7, idx = lin >> 3;       // idx 0..95
  const int bxx = (xcd & 1) * 12 + idx % 12;
  const int byy = (xcd >> 1) * 8 + idx / 12;
  const int bn0 = bxx * 128, bm0 = byy * 128;
  const int srow = w * 8 + (lane >> 3);
  const int scol = (lane & 7) * 8;
  f32x4 acc[4][4] = {};
  for (int k0 = 0; k0 < K; k0 += 64) {
    __syncthreads();
#pragma unroll
    for (int i = 0; i < 4; ++i) {
      gload16(&A[(size_t)(bm0 + i * 32 + srow) * K + k0 + scol], &As[(i * 32 + w * 8) * 64]);
      gload16(&Bm[(size_t)(bn0 + i * 32 + srow) * K + k0 + scol], &Bs[(i * 32 + w * 8) * 64]);
    }
    __syncthreads();
#pragma unroll
    for (int kk = 0; kk < 64; kk += 32) {
      short8 am[4], bn[4];
#pragma unroll
      for (int t = 0; t < 4; ++t) {
        am[t] = *reinterpret_cast<const short8*>(&As[(wr * 64 + t * 16 + l15) * 64 + kk + l4 * 8]);
        bn[t] = *reinterpret_cast<const short8*>(&Bs[(wc * 64 + t * 16 + l15) * 64 + kk + l4 * 8]);
      }
#pragma unroll
      for (int m = 0; m < 4; ++m)
#pragma unroll
        for (int n = 0; n < 4; ++n)
          acc[m][n] = __builtin_amdgcn_mfma_f32_16x16x32_bf16(am[m], bn[n], acc[m][n], 0, 0, 0);
    }
  }
  const int colbase = bn0 + wc * 64;  // 64-aligned
  const int region = colbase >> 10;   // 0=Q, 1=K, 2=V
  if (region < 2) {
    bf16* dst = region ? Kr : Qr;
    const int h = (colbase & 1023) >> 6;
#pragma unroll
    for (int m = 0; m < 4; ++m)
#pragma unroll
      for (int n = 0; n < 2; ++n)
#pragma unroll
        for (int r = 0; r < 4; ++r) {
          int row = bm0 + wr * 64 + m * 16 + l4 * 4 + r;
          int b = row >> 11, s = row & (NS - 1);
          int j = n * 16 + l15;  // [0,32)
          float cs = cs_tab[s * 32 + j], sn = sn_tab[s * 32 + j];
          float v0 = acc[m][n][r], v1 = acc[m][n + 2][r];
          size_t base = ((size_t)(b * NH + h) * NS + s) * NHD + j;
          dst[base] = __float2bfloat16(v0 * cs - v1 * sn);
          dst[base + 32] = __float2bfloat16(v1 * cs + v0 * sn);
        }
  } else {
#pragma unroll
    for (int m = 0; m < 4; ++m)
#pragma unroll
      for (int n = 0; n < 4; ++n)
#pragma unroll
        for (int r = 0; r < 4; ++r) {
          int row = bm0 + wr * 64 + m * 16 + l4 * 4 + r;
          int col = colbase + n * 16 + l15 - 2048;
          Vtmp[(size_t)row * ND + col] = __float2bfloat16(acc[m][n][r]);
        }
  }
}

// ---------------- out-proj GEMM: C[M,N] = A[M,K] * B[N,K]^T, fp32 out ----------------
// XCD-rect swizzle: grid 8x32 tiles; each XCD owns 4x x 8y -> ~3MB L2 set.
__global__ __launch_bounds__(256) void gemm_bt(const bf16* __restrict__ A,
                                               const bf16* __restrict__ Bm,
                                               float* __restrict__ Cv,
                                               int M, int N, int K) {
  __shared__ short As[128 * 64];
  __shared__ short Bs[128 * 64];
  const int tid = threadIdx.x;
  const int lane = tid & 63;
  const int w = tid >> 6;
  const int wr = w >> 1, wc = w & 1;
  const int l15 = lane & 15, l4 = lane >> 4;
  const int lin = blockIdx.y * 8 + blockIdx.x;
  const int xcd = lin & 7, idx = lin >> 3;  // idx 0..31
  const int bxx = (xcd & 1) * 4 + (idx & 3);
  const int byy = (xcd >> 1) * 8 + (idx >> 2);
  const int bn0 = bxx * 128, bm0 = byy * 128;
  const int srow = w * 8 + (lane >> 3);
  const int scol = (lane & 7) * 8;
  f32x4 acc[4][4] = {};
  for (int k0 = 0; k0 < K; k0 += 64) {
    __syncthreads();
#pragma unroll
    for (int i = 0; i < 4; ++i) {
      gload16(&A[(size_t)(bm0 + i * 32 + srow) * K + k0 + scol], &As[(i * 32 + w * 8) * 64]);
      gload16(&Bm[(size_t)(bn0 + i * 32 + srow) * K + k0 + scol], &Bs[(i * 32 + w * 8) * 64]);
    }
    __syncthreads();
#pragma unroll
    for (int kk = 0; kk < 64; kk += 32) {
      short8 am[4], bn[4];
#pragma unroll
      for (int t = 0; t < 4; ++t) {
        am[t] = *reinterpret_cast<const short8*>(&As[(wr * 64 + t * 16 + l15) * 64 + kk + l4 * 8]);
        bn[t] = *reinterpret_cast<const short8*>(&Bs[(wc * 64 + t * 16 + l15) * 64 + kk + l4 * 8]);
      }
#pragma unroll
      for (int m = 0; m < 4; ++m)
#pragma unroll
        for (int n = 0; n < 4; ++n)
          acc[m][n] = __builtin_amdgcn_mfma_f32_16x16x32_bf16(am[m], bn[n], acc[m][n], 0, 0, 0);
    }
  }
#pragma unroll
  for (int m = 0; m < 4; ++m)
#pragma unroll
    for (int n = 0; n < 4; ++n)
#pragma unroll
      for (int r = 0; r < 4; ++r) {
        int row = bm0 + wr * 64 + m * 16 + l4 * 4 + r;
        int col = bn0 + wc * 64 + n * 16 + l15;
        Cv[(size_t)row * N + col] = acc[m][n][r];
      }
}

// ---------------- V transpose: Vtmp [4096,1024] -> Vt (bf16 [B,H,HD,S]) ----------------
__global__ __launch_bounds__(256) void vtrans_kernel(const bf16* __restrict__ Vtmp,
                                                     bf16* __restrict__ Vt) {
  int bh = blockIdx.y;
  int b = bh >> 4, h = bh & 15;
  int s0 = blockIdx.x * 64;
  __shared__ bf16 tile[64][72];
#pragma unroll
  for (int it = 0; it < 16; ++it) {
    int e = it * 256 + threadIdx.x;
    int sr = e >> 6, hd = e & 63;
    tile[sr][hd] = Vtmp[(size_t)(b * NS + s0 + sr) * ND + h * NHD + hd];
  }
  __syncthreads();
#pragma unroll
  for (int it = 0; it < 16; ++it) {
    int e = it * 256 + threadIdx.x;
    int hd = e >> 6, sc = e & 63;
    Vt[((size_t)bh * NHD + hd) * NS + s0 + sc] = tile[sc][hd];
  }
}

// ---------------- attn_mask -> float bias ----------------
__global__ void maskbias_kernel(const int* __restrict__ amask, float* __restrict__ mb, int n) {
  int i = blockIdx.x * blockDim.x + threadIdx.x;
  if (i < n) mb[i] = amask[i] ? 0.f : -1e30f;
}

// ---------------- causal flash attention (round-6 verified: 4 waves, 128 q-rows) ---------
__global__ __launch_bounds__(256, 2) void attn_kernel(const bf16* __restrict__ Qr,
                                                      const bf16* __restrict__ Kr,
                                                      const bf16* __restrict__ Vt,
                                                      const float* __restrict__ mb,
                                                      bf16* __restrict__ AO) {
  __shared__ short Ks[2][64 * 64];
  __shared__ short Vs[2][64 * 64];
  __shared__ float Mb[2][64];

  const int tid = threadIdx.x;
  const int lane = tid & 63;
  const int w = tid >> 6;
  const int q = lane & 31;
  const int hi = lane >> 5;

  const int lin = blockIdx.x;
  const int xcd = lin & 7;
  const int k = lin >> 3;
  const int bh = xcd * 4 + (k & 3);
  const int kk = k >> 2;
  const int tile = (k < 32) ? (15 - kk) : (kk - 8);
  const int b = bh >> 4, h = bh & 15;
  const int qw = tile * 128 + w * 32;
  const int nc = 2 * tile + 2;

  const bf16* Qb = Qr + (size_t)bh * NS * NHD;
  const bf16* Kb = Kr + (size_t)bh * NS * NHD;
  const bf16* Vb = Vt + (size_t)bh * NHD * NS;

  const int srow = tid >> 2;
  const int sc0 = (tid & 3) * 16;
  const int swz = (srow & 7) << 3;

  short8 Qf[4];
#pragma unroll
  for (int s = 0; s < 4; ++s)
    Qf[s] = *reinterpret_cast<const short8*>(&Qb[(size_t)(qw + q) * NHD + s * 16 + hi * 8]);

  f32x16 o0 = {}, o1 = {};
  float mx = -1e30f, lsum = 0.f;

  short8 kreg[2], vreg[2];
  float4 mreg;
  auto prefetch = [&](int kv0) {
    kreg[0] = *reinterpret_cast<const short8*>(&Kb[(size_t)(kv0 + srow) * NHD + sc0]);
    kreg[1] = *reinterpret_cast<const short8*>(&Kb[(size_t)(kv0 + srow) * NHD + sc0 + 8]);
    vreg[0] = *reinterpret_cast<const short8*>(&Vb[(size_t)srow * NS + kv0 + sc0]);
    vreg[1] = *reinterpret_cast<const short8*>(&Vb[(size_t)srow * NS + kv0 + sc0 + 8]);
    if (tid < 16) mreg = *reinterpret_cast<const float4*>(&mb[b * NS + kv0 + tid * 4]);
  };
  auto stage = [&](int buf) {
    *reinterpret_cast<short8*>(&Ks[buf][srow * 64 + (sc0 ^ swz)]) = kreg[0];
    *reinterpret_cast<short8*>(&Ks[buf][srow * 64 + ((sc0 + 8) ^ swz)]) = kreg[1];
    *reinterpret_cast<short8*>(&Vs[buf][srow * 64 + (sc0 ^ swz)]) = vreg[0];
    *reinterpret_cast<short8*>(&Vs[buf][srow * 64 + ((sc0 + 8) ^ swz)]) = vreg[1];
    if (tid < 16) *reinterpret_cast<float4*>(&Mb[buf][tid * 4]) = mreg;
  };

  prefetch(0);
  stage(0);
  __syncthreads();

  const int rsw = (q & 7) << 3;

  for (int c = 0; c < nc; ++c) {
    const int cur = c & 1;
    const int kv0 = c * 64;
    if (c + 1 < nc) prefetch((c + 1) * 64);

    if (kv0 < qw + 32) {
      f32x16 a0 = {}, a1 = {};
#pragma unroll
      for (int s = 0; s < 4; ++s) {
        short8 kf0 = *reinterpret_cast<const short8*>(
            &Ks[cur][q * 64 + ((s * 16 + hi * 8) ^ rsw)]);
        short8 kf1 = *reinterpret_cast<const short8*>(
            &Ks[cur][(32 + q) * 64 + ((s * 16 + hi * 8) ^ rsw)]);
        a0 = __builtin_amdgcn_mfma_f32_32x32x16_bf16(kf0, Qf[s], a0, 0, 0, 0);
        a1 = __builtin_amdgcn_mfma_f32_32x32x16_bf16(kf1, Qf[s], a1, 0, 0, 0);
      }

      float4 bv[2][4];
#pragma unroll
      for (int t = 0; t < 2; ++t)
#pragma unroll
        for (int g = 0; g < 4; ++g)
          bv[t][g] = *reinterpret_cast<const float4*>(&Mb[cur][t * 32 + g * 8 + hi * 4]);
      const int qg = qw + q;
#pragma unroll
      for (int t = 0; t < 2; ++t) {
        f32x16& a = t ? a1 : a0;
        const bool needc = (kv0 + t * 32 + 31 > qw);
#pragma unroll
        for (int r = 0; r < 16; ++r) {
          float v = fmaf(a[r], SM_SCALE, ((const float*)&bv[t][r >> 2])[r & 3]);
          if (needc) {
            int kvg = kv0 + t * 32 + (r & 3) + 8 * (r >> 2) + 4 * hi;
            if (kvg > qg) v = -1e30f;
          }
          a[r] = v;
        }
      }

      float cm = a0[0];
#pragma unroll
      for (int r = 1; r < 16; ++r) cm = fmaxf(cm, a0[r]);
#pragma unroll
      for (int r = 0; r < 16; ++r) cm = fmaxf(cm, a1[r]);
      float pm = fmaxf(cm, __shfl_xor(cm, 32));

      if (!__all(pm <= mx + 8.f)) {
        float mn = fmaxf(mx, pm);
        float fac = __builtin_amdgcn_exp2f(mx - mn);
        mx = mn;
        lsum *= fac;
#pragma unroll
        for (int r = 0; r < 16; ++r) {
          float fq = __shfl(fac, (r & 3) + 8 * (r >> 2) + 4 * hi);
          o0[r] *= fq;
          o1[r] *= fq;
        }
      }

      float rs = 0.f;
      short8 pa[4];
#pragma unroll
      for (int t = 0; t < 2; ++t) {
        f32x16& a = t ? a1 : a0;
#pragma unroll
        for (int r = 0; r < 16; ++r) {
          float e = __builtin_amdgcn_exp2f(a[r] - mx);
          a[r] = e;
          rs += e;
        }
#pragma unroll
        for (int g = 0; g < 2; ++g) {
          union { unsigned int u; __hip_bfloat162 h2; } X, X2, Y, Y2;
          X.h2 = __float22bfloat162_rn(float2{a[g * 8 + 0], a[g * 8 + 1]});
          X2.h2 = __float22bfloat162_rn(float2{a[g * 8 + 2], a[g * 8 + 3]});
          Y.h2 = __float22bfloat162_rn(float2{a[g * 8 + 4], a[g * 8 + 5]});
          Y2.h2 = __float22bfloat162_rn(float2{a[g * 8 + 6], a[g * 8 + 7]});
          asm volatile("v_permlane32_swap_b32 %0, %1" : "+v"(X.u), "+v"(Y.u));
          asm volatile("v_permlane32_swap_b32 %0, %1" : "+v"(X2.u), "+v"(Y2.u));
          union { unsigned int u[4]; short8 s; } P;
          P.u[0] = X.u;
          P.u[1] = X2.u;
          P.u[2] = Y.u;
          P.u[3] = Y2.u;
          pa[t * 2 + g] = P.s;
        }
      }
      lsum += rs + __shfl_xor(rs, 32);

#pragma unroll
      for (int ks = 0; ks < 4; ++ks) {
        const int vcol = (ks * 16 + hi * 8) ^ rsw;
        short8 vf0 = *reinterpret_cast<const short8*>(&Vs[cur][q * 64 + vcol]);
        short8 vf1 = *reinterpret_cast<const short8*>(&Vs[cur][(32 + q) * 64 + vcol]);
        o0 = __builtin_amdgcn_mfma_f32_32x32x16_bf16(pa[ks], vf0, o0, 0, 0, 0);
        o1 = __builtin_amdgcn_mfma_f32_32x32x16_bf16(pa[ks], vf1, o1, 0, 0, 0);
      }
    }

    if (c + 1 < nc) stage(cur ^ 1);
    __syncthreads();
  }

  float inv = 1.0f / lsum;
#pragma unroll
  for (int r = 0; r < 16; ++r) {
    const int crow = (r & 3) + 8 * (r >> 2) + 4 * hi;
    float iq = __shfl(inv, crow);
    size_t base = (size_t)(b * NS + qw + crow) * ND + h * NHD;
    AO[base + q] = __float2bfloat16(o0[r] * iq);
    AO[base + 32 + q] = __float2bfloat16(o1[r] * iq);
  }
}

extern "C" void kernel_launch(void* const* d_in, const int* in_sizes, int n_in,
                              void* d_out, int out_size, void* d_ws, size_t ws_size,
                              hipStream_t stream) {
  const float* x = (const float*)d_in[0];
  const int* amask = (const int*)d_in[1];
  const float* Wqkv = (const float*)d_in[2];
  const float* Wout = (const float*)d_in[3];
  float* out = (float*)d_out;

  char* p = (char*)d_ws;
  bf16* xb = (bf16*)(p);                  // 8,388,608
  bf16* wqkvb = (bf16*)(p + 8388608);     // 6,291,456 (dead after gemm_qkv)
  bf16* woutb = (bf16*)(p + 14680064);    // 2,097,152
  bf16* Vtmp = (bf16*)(p + 16777216);     // 8,388,608 -> 25,165,824
  float* cs_tab = (float*)(p + 25165824); // 262,144
  float* sn_tab = (float*)(p + 25427968); // 262,144 -> 25,690,112
  bf16* Qr = (bf16*)(p + 41943040);       // 8,388,608
  bf16* Kr = (bf16*)(p + 50331648);       // 8,388,608
  bf16* Vt = (bf16*)(p + 58720256);       // 8,388,608 -> 67,108,864 end
  bf16* AO = xb;                          // aliases xb (dead after gemm_qkv)
  float* mbias = (float*)(p + 8388608);   // aliases wqkvb (dead after gemm_qkv)

  cast_kernel<<<4096, 256, 0, stream>>>((const float4*)x, xb, (NB * NS * ND) / 4);
  cast_kernel<<<3072, 256, 0, stream>>>((const float4*)Wqkv, wqkvb, (N3D * ND) / 4);
  cast_kernel<<<1024, 256, 0, stream>>>((const float4*)Wout, woutb, (ND * ND) / 4);
  ropetab_kernel<<<256, 256, 0, stream>>>(cs_tab, sn_tab);

  gemm_qkv<<<dim3(N3D / 128, (NB * NS) / 128), 256, 0, stream>>>(xb, wqkvb, cs_tab, sn_tab,
                                                                 Qr, Kr, Vtmp);
  vtrans_kernel<<<dim3(NS / 64, NB * NH), 256, 0, stream>>>(Vtmp, Vt);
  maskbias_kernel<<<16, 256, 0, stream>>>(amask, mbias, NB * NS);
  attn_kernel<<<512, 256, 0, stream>>>(Qr, Kr, Vt, mbias, AO);
  gemm_bt<<<dim3(ND / 128, (NB * NS) / 128), 256, 0, stream>>>(AO, woutb, out,
                                                               NB * NS, ND, ND);
}

// Round 10
// 141.190 us; speedup vs baseline: 1.1325x; 1.1102x over previous
//
#include <hip/hip_runtime.h>
#include <hip/hip_bf16.h>
#include <math.h>
#include <stdint.h>

typedef __hip_bfloat16 bf16;
typedef __attribute__((ext_vector_type(8))) short short8;
typedef __attribute__((ext_vector_type(4))) float f32x4;
typedef __attribute__((ext_vector_type(16))) float f32x16;

#define NB 2
#define NS 2048
#define ND 1024
#define NH 16
#define NHD 64
#define N3D 3072

// softmax scale folded into exp2 domain: (1/sqrt(64)) * log2(e)
#define SM_SCALE 0.18033688011112042f

// ---------------- async global->LDS, 16B per lane ----------------
__device__ __forceinline__ void gload16(const bf16* g, void* l) {
  __builtin_amdgcn_global_load_lds(
      (const __attribute__((address_space(1))) uint32_t*)g,
      (__attribute__((address_space(3))) uint32_t*)l, 16, 0, 0);
}

// ---------------- fp32 -> bf16 cast (4-wide) ----------------
__global__ void cast_kernel(const float4* __restrict__ in, bf16* __restrict__ out, int n4) {
  int i = blockIdx.x * blockDim.x + threadIdx.x;
  if (i >= n4) return;
  float4 v = in[i];
  alignas(8) bf16 r[4];
  r[0] = __float2bfloat16(v.x);
  r[1] = __float2bfloat16(v.y);
  r[2] = __float2bfloat16(v.z);
  r[3] = __float2bfloat16(v.w);
  *reinterpret_cast<uint2*>(out + (size_t)i * 4) = *reinterpret_cast<const uint2*>(r);
}

// ---------------- RoPE cos/sin tables: [S][32] each ----------------
__global__ void ropetab_kernel(float* __restrict__ cs_tab, float* __restrict__ sn_tab) {
  int idx = blockIdx.x * blockDim.x + threadIdx.x;  // 65536
  int j = idx & 31;
  int s = idx >> 5;
  float inv = exp2f((float)(2 * j) * (-13.287712379549449f / 64.0f));
  float ang = (float)s * inv;
  float sn, cs;
  sincosf(ang, &sn, &cs);
  cs_tab[idx] = cs;
  sn_tab[idx] = sn;
}

// ================= pipelined GEMM core (shared shape) =================
// 128x128 tile, BK=64, K=1024 (16 K-tiles), 8 waves (2m x 4n), 64x32 per wave.
// 3-slot LDS ring: compute tile t from slot t%3 while staging t+2 into (t+2)%3
// (that slot was last read at t-1 -> no aliasing). End of iter: vmcnt(4) keeps
// tile t+2's 4 loads in flight (never drain to 0) + raw s_barrier.
// T2: linear LDS dest (global_load_lds), inverse-swizzled GLOBAL src, swizzled read.
// Wave wn owns C cols (wn>>1)*64 + (wn&1)*16 + {0..15, 32..47} so the rope pair
// (j, j+32) stays in-wave (acc[mi][0] / acc[mi][1]).

#define GEMM_PIPE_BODY(...)                                                               \
  __shared__ short As[3][128 * 64];                                                       \
  __shared__ short Bs[3][128 * 64];                                                       \
  const int tid = threadIdx.x;                                                            \
  const int lane = tid & 63;                                                              \
  const int w = tid >> 6;                                                                 \
  const int wm = w >> 2, wn = w & 3;                                                      \
  const int l15 = lane & 15, l4 = lane >> 4;                                              \
  const int r0 = tid >> 3, seg = tid & 7;                                                 \
  const int sw = ((seg ^ (r0 & 7)) << 3);                                                 \
  const bf16* Ar0 = Ap + (size_t)(bm0 + r0) * 1024 + sw;                                  \
  const bf16* Ar1 = Ap + (size_t)(bm0 + r0 + 64) * 1024 + sw;                             \
  const bf16* Br0 = Bp + (size_t)(bn0 + r0) * 1024 + sw;                                  \
  const bf16* Br1 = Bp + (size_t)(bn0 + r0 + 64) * 1024 + sw;                             \
  f32x4 acc[4][2] = {};                                                                   \
  gload16(Ar0 + 0, &As[0][w * 512]);                                                      \
  gload16(Ar1 + 0, &As[0][4096 + w * 512]);                                               \
  gload16(Br0 + 0, &Bs[0][w * 512]);                                                      \
  gload16(Br1 + 0, &Bs[0][4096 + w * 512]);                                               \
  gload16(Ar0 + 64, &As[1][w * 512]);                                                     \
  gload16(Ar1 + 64, &As[1][4096 + w * 512]);                                              \
  gload16(Br0 + 64, &Bs[1][w * 512]);                                                     \
  gload16(Br1 + 64, &Bs[1][4096 + w * 512]);                                              \
  asm volatile("s_waitcnt vmcnt(4)" ::: "memory");                                        \
  __builtin_amdgcn_s_barrier();                                                           \
  for (int t = 0; t < 16; ++t) {                                                          \
    const int slot = t % 3;                                                               \
    if (t + 2 < 16) {                                                                     \
      const int ns = (t + 2) % 3;                                                         \
      const int nk = (t + 2) * 64;                                                        \
      gload16(Ar0 + nk, &As[ns][w * 512]);                                                \
      gload16(Ar1 + nk, &As[ns][4096 + w * 512]);                                         \
      gload16(Br0 + nk, &Bs[ns][w * 512]);                                                \
      gload16(Br1 + nk, &Bs[ns][4096 + w * 512]);                                         \
    }                                                                                     \
    _Pragma("unroll") for (int kk = 0; kk < 2; ++kk) {                                    \
      short8 af[4], bfr[2];                                                               \
      _Pragma("unroll") for (int mi = 0; mi < 4; ++mi) {                                  \
        int row = wm * 64 + mi * 16 + l15;                                                \
        af[mi] = *(const short8*)&As[slot][row * 64 + (((kk * 4 + l4) ^ (row & 7)) << 3)];\
      }                                                                                   \
      _Pragma("unroll") for (int ni = 0; ni < 2; ++ni) {                                  \
        int row = (wn >> 1) * 64 + (wn & 1) * 16 + ni * 32 + l15;                         \
        bfr[ni] = *(const short8*)&Bs[slot][row * 64 + (((kk * 4 + l4) ^ (row & 7)) << 3)];\
      }                                                                                   \
      __builtin_amdgcn_s_setprio(1);                                                      \
      _Pragma("unroll") for (int mi = 0; mi < 4; ++mi)                                    \
        _Pragma("unroll") for (int ni = 0; ni < 2; ++ni)                                  \
          acc[mi][ni] =                                                                   \
              __builtin_amdgcn_mfma_f32_16x16x32_bf16(af[mi], bfr[ni], acc[mi][ni], 0, 0, 0);\
      __builtin_amdgcn_s_setprio(0);                                                      \
      if (kk == 0) __builtin_amdgcn_s_barrier();                                          \
    }                                                                                     \
    if (t + 2 < 16) {                                                                     \
      asm volatile("s_waitcnt vmcnt(4)" ::: "memory");                                    \
      __builtin_amdgcn_s_barrier();                                                       \
    } else if (t < 15) {                                                                  \
      asm volatile("s_waitcnt vmcnt(0)" ::: "memory");                                    \
      __builtin_amdgcn_s_barrier();                                                       \
    }                                                                                     \
  }                                                                                       \
  __VA_ARGS__

// ---------------- QKV GEMM (fused RoPE epilogue), M=4096 N=3072 K=1024 ----------------
__global__ __launch_bounds__(512) void gemm_qkv(const bf16* __restrict__ Ap,
                                                const bf16* __restrict__ Bp,
                                                const float* __restrict__ cs_tab,
                                                const float* __restrict__ sn_tab,
                                                bf16* __restrict__ Qr, bf16* __restrict__ Kr,
                                                bf16* __restrict__ Vtmp) {
  // bijective XCD-rect map: 768 blocks = 24x x 32y tiles; each XCD owns 12x x 8y
  const int lin = blockIdx.x;
  const int xcd = lin & 7, idx = lin >> 3;  // 0..95
  const int bxx = (xcd & 1) * 12 + idx % 12;
  const int byy = (xcd >> 1) * 8 + idx / 12;
  const int bn0 = bxx * 128, bm0 = byy * 128;
  GEMM_PIPE_BODY(
    const int colw = bn0 + (wn >> 1) * 64 + (wn & 1) * 16;  // wave col base
    const int region = colw >> 10;                          // 0=Q 1=K 2=V
    if (region < 2) {
      bf16* dst = region ? Kr : Qr;
      const int h = (colw & 1023) >> 6;
      const int j = (wn & 1) * 16 + l15;  // [0,32)
      _Pragma("unroll") for (int mi = 0; mi < 4; ++mi) {
        _Pragma("unroll") for (int r = 0; r < 4; ++r) {
          int row = bm0 + wm * 64 + mi * 16 + l4 * 4 + r;
          int b = row >> 11;
          int s = row & (NS - 1);
          float cs = cs_tab[s * 32 + j];
          float sn = sn_tab[s * 32 + j];
          float v0 = acc[mi][0][r];
          float v1 = acc[mi][1][r];
          size_t base = ((size_t)(b * NH + h) * NS + s) * NHD + j;
          dst[base] = __float2bfloat16(v0 * cs - v1 * sn);
          dst[base + 32] = __float2bfloat16(v1 * cs + v0 * sn);
        }
      }
    } else {
      _Pragma("unroll") for (int mi = 0; mi < 4; ++mi) {
        _Pragma("unroll") for (int ni = 0; ni < 2; ++ni) {
          _Pragma("unroll") for (int r = 0; r < 4; ++r) {
            int row = bm0 + wm * 64 + mi * 16 + l4 * 4 + r;
            int col = colw + ni * 32 + l15 - 2048;
            Vtmp[(size_t)row * ND + col] = __float2bfloat16(acc[mi][ni][r]);
          }
        }
      }
    }
  )
}

// ---------------- out-proj GEMM, M=4096 N=1024 K=1024, fp32 out ----------------
__global__ __launch_bounds__(512) void gemm_bt(const bf16* __restrict__ Ap,
                                               const bf16* __restrict__ Bp,
                                               float* __restrict__ Cv) {
  // 256 blocks = 8x x 32y tiles; each XCD owns 4x x 8y
  const int lin = blockIdx.x;
  const int xcd = lin & 7, idx = lin >> 3;  // 0..31
  const int bxx = (xcd & 1) * 4 + (idx & 3);
  const int byy = (xcd >> 1) * 8 + (idx >> 2);
  const int bn0 = bxx * 128, bm0 = byy * 128;
  GEMM_PIPE_BODY(
    _Pragma("unroll") for (int mi = 0; mi < 4; ++mi) {
      _Pragma("unroll") for (int ni = 0; ni < 2; ++ni) {
        _Pragma("unroll") for (int r = 0; r < 4; ++r) {
          int row = bm0 + wm * 64 + mi * 16 + l4 * 4 + r;
          int col = bn0 + (wn >> 1) * 64 + (wn & 1) * 16 + ni * 32 + l15;
          Cv[(size_t)row * ND + col] = acc[mi][ni][r];
        }
      }
    }
  )
}

// ---------------- V transpose: Vtmp [4096,1024] -> Vt (bf16 [B,H,HD,S]) ----------------
__global__ __launch_bounds__(256) void vtrans_kernel(const bf16* __restrict__ Vtmp,
                                                     bf16* __restrict__ Vt) {
  int bh = blockIdx.y;
  int b = bh >> 4, h = bh & 15;
  int s0 = blockIdx.x * 64;
  __shared__ bf16 tile[64][72];
#pragma unroll
  for (int it = 0; it < 16; ++it) {
    int e = it * 256 + threadIdx.x;
    int sr = e >> 6, hd = e & 63;
    tile[sr][hd] = Vtmp[(size_t)(b * NS + s0 + sr) * ND + h * NHD + hd];
  }
  __syncthreads();
#pragma unroll
  for (int it = 0; it < 16; ++it) {
    int e = it * 256 + threadIdx.x;
    int hd = e >> 6, sc = e & 63;
    Vt[((size_t)bh * NHD + hd) * NS + s0 + sc] = tile[sc][hd];
  }
}

// ---------------- attn_mask -> float bias ----------------
__global__ void maskbias_kernel(const int* __restrict__ amask, float* __restrict__ mb, int n) {
  int i = blockIdx.x * blockDim.x + threadIdx.x;
  if (i < n) mb[i] = amask[i] ? 0.f : -1e30f;
}

// ---------------- causal flash attention (round-6 verified: 4 waves, 128 q-rows) ---------
__global__ __launch_bounds__(256, 2) void attn_kernel(const bf16* __restrict__ Qr,
                                                      const bf16* __restrict__ Kr,
                                                      const bf16* __restrict__ Vt,
                                                      const float* __restrict__ mb,
                                                      bf16* __restrict__ AO) {
  __shared__ short Ks[2][64 * 64];
  __shared__ short Vs[2][64 * 64];
  __shared__ float Mb[2][64];

  const int tid = threadIdx.x;
  const int lane = tid & 63;
  const int w = tid >> 6;
  const int q = lane & 31;
  const int hi = lane >> 5;

  const int lin = blockIdx.x;
  const int xcd = lin & 7;
  const int k = lin >> 3;
  const int bh = xcd * 4 + (k & 3);
  const int kk = k >> 2;
  const int tile = (k < 32) ? (15 - kk) : (kk - 8);
  const int b = bh >> 4, h = bh & 15;
  const int qw = tile * 128 + w * 32;
  const int nc = 2 * tile + 2;

  const bf16* Qb = Qr + (size_t)bh * NS * NHD;
  const bf16* Kb = Kr + (size_t)bh * NS * NHD;
  const bf16* Vb = Vt + (size_t)bh * NHD * NS;

  const int srow = tid >> 2;
  const int sc0 = (tid & 3) * 16;
  const int swz = (srow & 7) << 3;

  short8 Qf[4];
#pragma unroll
  for (int s = 0; s < 4; ++s)
    Qf[s] = *reinterpret_cast<const short8*>(&Qb[(size_t)(qw + q) * NHD + s * 16 + hi * 8]);

  f32x16 o0 = {}, o1 = {};
  float mx = -1e30f, lsum = 0.f;

  short8 kreg[2], vreg[2];
  float4 mreg;
  auto prefetch = [&](int kv0) {
    kreg[0] = *reinterpret_cast<const short8*>(&Kb[(size_t)(kv0 + srow) * NHD + sc0]);
    kreg[1] = *reinterpret_cast<const short8*>(&Kb[(size_t)(kv0 + srow) * NHD + sc0 + 8]);
    vreg[0] = *reinterpret_cast<const short8*>(&Vb[(size_t)srow * NS + kv0 + sc0]);
    vreg[1] = *reinterpret_cast<const short8*>(&Vb[(size_t)srow * NS + kv0 + sc0 + 8]);
    if (tid < 16) mreg = *reinterpret_cast<const float4*>(&mb[b * NS + kv0 + tid * 4]);
  };
  auto stage = [&](int buf) {
    *reinterpret_cast<short8*>(&Ks[buf][srow * 64 + (sc0 ^ swz)]) = kreg[0];
    *reinterpret_cast<short8*>(&Ks[buf][srow * 64 + ((sc0 + 8) ^ swz)]) = kreg[1];
    *reinterpret_cast<short8*>(&Vs[buf][srow * 64 + (sc0 ^ swz)]) = vreg[0];
    *reinterpret_cast<short8*>(&Vs[buf][srow * 64 + ((sc0 + 8) ^ swz)]) = vreg[1];
    if (tid < 16) *reinterpret_cast<float4*>(&Mb[buf][tid * 4]) = mreg;
  };

  prefetch(0);
  stage(0);
  __syncthreads();

  const int rsw = (q & 7) << 3;

  for (int c = 0; c < nc; ++c) {
    const int cur = c & 1;
    const int kv0 = c * 64;
    if (c + 1 < nc) prefetch((c + 1) * 64);

    if (kv0 < qw + 32) {
      f32x16 a0 = {}, a1 = {};
#pragma unroll
      for (int s = 0; s < 4; ++s) {
        short8 kf0 = *reinterpret_cast<const short8*>(
            &Ks[cur][q * 64 + ((s * 16 + hi * 8) ^ rsw)]);
        short8 kf1 = *reinterpret_cast<const short8*>(
            &Ks[cur][(32 + q) * 64 + ((s * 16 + hi * 8) ^ rsw)]);
        a0 = __builtin_amdgcn_mfma_f32_32x32x16_bf16(kf0, Qf[s], a0, 0, 0, 0);
        a1 = __builtin_amdgcn_mfma_f32_32x32x16_bf16(kf1, Qf[s], a1, 0, 0, 0);
      }

      float4 bv[2][4];
#pragma unroll
      for (int t = 0; t < 2; ++t)
#pragma unroll
        for (int g = 0; g < 4; ++g)
          bv[t][g] = *reinterpret_cast<const float4*>(&Mb[cur][t * 32 + g * 8 + hi * 4]);
      const int qg = qw + q;
#pragma unroll
      for (int t = 0; t < 2; ++t) {
        f32x16& a = t ? a1 : a0;
        const bool needc = (kv0 + t * 32 + 31 > qw);
#pragma unroll
        for (int r = 0; r < 16; ++r) {
          float v = fmaf(a[r], SM_SCALE, ((const float*)&bv[t][r >> 2])[r & 3]);
          if (needc) {
            int kvg = kv0 + t * 32 + (r & 3) + 8 * (r >> 2) + 4 * hi;
            if (kvg > qg) v = -1e30f;
          }
          a[r] = v;
        }
      }

      float cm = a0[0];
#pragma unroll
      for (int r = 1; r < 16; ++r) cm = fmaxf(cm, a0[r]);
#pragma unroll
      for (int r = 0; r < 16; ++r) cm = fmaxf(cm, a1[r]);
      float pm = fmaxf(cm, __shfl_xor(cm, 32));

      if (!__all(pm <= mx + 8.f)) {
        float mn = fmaxf(mx, pm);
        float fac = __builtin_amdgcn_exp2f(mx - mn);
        mx = mn;
        lsum *= fac;
#pragma unroll
        for (int r = 0; r < 16; ++r) {
          float fq = __shfl(fac, (r & 3) + 8 * (r >> 2) + 4 * hi);
          o0[r] *= fq;
          o1[r] *= fq;
        }
      }

      float rs = 0.f;
      short8 pa[4];
#pragma unroll
      for (int t = 0; t < 2; ++t) {
        f32x16& a = t ? a1 : a0;
#pragma unroll
        for (int r = 0; r < 16; ++r) {
          float e = __builtin_amdgcn_exp2f(a[r] - mx);
          a[r] = e;
          rs += e;
        }
#pragma unroll
        for (int g = 0; g < 2; ++g) {
          union { unsigned int u; __hip_bfloat162 h2; } X, X2, Y, Y2;
          X.h2 = __float22bfloat162_rn(float2{a[g * 8 + 0], a[g * 8 + 1]});
          X2.h2 = __float22bfloat162_rn(float2{a[g * 8 + 2], a[g * 8 + 3]});
          Y.h2 = __float22bfloat162_rn(float2{a[g * 8 + 4], a[g * 8 + 5]});
          Y2.h2 = __float22bfloat162_rn(float2{a[g * 8 + 6], a[g * 8 + 7]});
          asm volatile("v_permlane32_swap_b32 %0, %1" : "+v"(X.u), "+v"(Y.u));
          asm volatile("v_permlane32_swap_b32 %0, %1" : "+v"(X2.u), "+v"(Y2.u));
          union { unsigned int u[4]; short8 s; } P;
          P.u[0] = X.u;
          P.u[1] = X2.u;
          P.u[2] = Y.u;
          P.u[3] = Y2.u;
          pa[t * 2 + g] = P.s;
        }
      }
      lsum += rs + __shfl_xor(rs, 32);

#pragma unroll
      for (int ks = 0; ks < 4; ++ks) {
        const int vcol = (ks * 16 + hi * 8) ^ rsw;
        short8 vf0 = *reinterpret_cast<const short8*>(&Vs[cur][q * 64 + vcol]);
        short8 vf1 = *reinterpret_cast<const short8*>(&Vs[cur][(32 + q) * 64 + vcol]);
        o0 = __builtin_amdgcn_mfma_f32_32x32x16_bf16(pa[ks], vf0, o0, 0, 0, 0);
        o1 = __builtin_amdgcn_mfma_f32_32x32x16_bf16(pa[ks], vf1, o1, 0, 0, 0);
      }
    }

    if (c + 1 < nc) stage(cur ^ 1);
    __syncthreads();
  }

  float inv = 1.0f / lsum;
#pragma unroll
  for (int r = 0; r < 16; ++r) {
    const int crow = (r & 3) + 8 * (r >> 2) + 4 * hi;
    float iq = __shfl(inv, crow);
    size_t base = (size_t)(b * NS + qw + crow) * ND + h * NHD;
    AO[base + q] = __float2bfloat16(o0[r] * iq);
    AO[base + 32 + q] = __float2bfloat16(o1[r] * iq);
  }
}

extern "C" void kernel_launch(void* const* d_in, const int* in_sizes, int n_in,
                              void* d_out, int out_size, void* d_ws, size_t ws_size,
                              hipStream_t stream) {
  const float* x = (const float*)d_in[0];
  const int* amask = (const int*)d_in[1];
  const float* Wqkv = (const float*)d_in[2];
  const float* Wout = (const float*)d_in[3];
  float* out = (float*)d_out;

  char* p = (char*)d_ws;
  bf16* xb = (bf16*)(p);                  // 8,388,608
  bf16* wqkvb = (bf16*)(p + 8388608);     // 6,291,456 (dead after gemm_qkv)
  bf16* woutb = (bf16*)(p + 14680064);    // 2,097,152
  bf16* Vtmp = (bf16*)(p + 16777216);     // 8,388,608 -> 25,165,824
  float* cs_tab = (float*)(p + 25165824); // 262,144
  float* sn_tab = (float*)(p + 25427968); // 262,144 -> 25,690,112
  bf16* Qr = (bf16*)(p + 41943040);       // 8,388,608
  bf16* Kr = (bf16*)(p + 50331648);       // 8,388,608
  bf16* Vt = (bf16*)(p + 58720256);       // 8,388,608 -> 67,108,864 end
  bf16* AO = xb;                          // aliases xb (dead after gemm_qkv)
  float* mbias = (float*)(p + 8388608);   // aliases wqkvb (dead after gemm_qkv)

  cast_kernel<<<4096, 256, 0, stream>>>((const float4*)x, xb, (NB * NS * ND) / 4);
  cast_kernel<<<3072, 256, 0, stream>>>((const float4*)Wqkv, wqkvb, (N3D * ND) / 4);
  cast_kernel<<<1024, 256, 0, stream>>>((const float4*)Wout, woutb, (ND * ND) / 4);
  ropetab_kernel<<<256, 256, 0, stream>>>(cs_tab, sn_tab);

  gemm_qkv<<<768, 512, 0, stream>>>(xb, wqkvb, cs_tab, sn_tab, Qr, Kr, Vtmp);
  vtrans_kernel<<<dim3(NS / 64, NB * NH), 256, 0, stream>>>(Vtmp, Vt);
  maskbias_kernel<<<16, 256, 0, stream>>>(amask, mbias, NB * NS);
  attn_kernel<<<512, 256, 0, stream>>>(Qr, Kr, Vt, mbias, AO);
  gemm_bt<<<256, 512, 0, stream>>>(AO, woutb, out);
}